// Round 6
// baseline (5812.307 us; speedup 1.0000x reference)
//
#include <hip/hip_runtime.h>
#include <hip/hip_bf16.h>

#define T_STEPS 1024
// ws layout (float offsets)
#define OFF_AFT   0ull          // AfM row-major [2048][2048] fp32
#define OFF_GCAT  4194304ull
#define OFF_CFT   8388608ull
#define OFF_DELTA 10485760ull
#define OFF_BX    27262976ull
#define OFF_HS    44040192ull
#define OFF_HBUF  60817408ull   // u64[2][8192] self-tagged bf16 h words

typedef short short8 __attribute__((ext_vector_type(8)));
typedef float f32x4 __attribute__((ext_vector_type(4)));

__device__ __forceinline__ void build_oct_tables(int tid, int (*Is)[8], float (*Sg)[8]) {
  if (tid < 64) {
    int i = tid >> 3, j = tid & 7;
    int k = 0; float s = 0.f;
    if (i == 0)      { k = j; s = 1.f; }
    else if (j == 0) { k = i; s = 1.f; }
    else if (i == j) { k = 0; s = -1.f; }
    else {
      const int T7[7][3] = {{1,2,4},{2,3,5},{3,4,6},{4,5,7},{5,6,1},{6,7,2},{7,1,3}};
      for (int t = 0; t < 7; ++t) {
        int a = T7[t][0], b = T7[t][1], c = T7[t][2];
        const int P[3][3] = {{a,b,c},{b,c,a},{c,a,b}};
        for (int r = 0; r < 3; ++r) {
          if (i == P[r][0] && j == P[r][1]) { k = P[r][2]; s = 1.f; }
          if (i == P[r][1] && j == P[r][0]) { k = P[r][2]; s = -1.f; }
        }
      }
    }
    Is[j][k] = i; Sg[j][k] = s;
  }
  __syncthreads();
}

__device__ __forceinline__ unsigned short bf16r(float x) {
  unsigned u = __float_as_uint(x);
  return (unsigned short)((u + 0x7FFFu + ((u >> 16) & 1u)) >> 16);
}

// AfM[sp][s] row-major: Af[k8*256+o][j8*256+n] = Sg[j8][k8]*WA[Is[j8][k8]][o][n]
__global__ __launch_bounds__(256) void fold_A(const float* __restrict__ WA, float* __restrict__ AfM) {
  __shared__ int Is[8][8]; __shared__ float Sg[8][8];
  build_oct_tables(threadIdx.x, Is, Sg);
  int g4 = blockIdx.x * 256 + threadIdx.x;   // 0..1048575 (2048 sp x 512 float4)
  int sp = g4 >> 9;
  int s4 = (g4 & 511) * 4;
  int k8 = sp >> 8, o = sp & 255;
  int j8 = s4 >> 8, n = s4 & 255;
  int i = Is[j8][k8]; float sg = Sg[j8][k8];
  float4 v = *(const float4*)(WA + (size_t)i * 65536 + (size_t)o * 256 + n);
  v.x *= sg; v.y *= sg; v.z *= sg; v.w *= sg;
  *(float4*)(AfM + (size_t)g4 * 4) = v;
}

// Gcat[d][0..2047] = Wdelta[s][d],  Gcat[d][2048+sp] = Bf[sp][d]
__global__ __launch_bounds__(256) void fold_GC(const float* __restrict__ Wd, const float* __restrict__ WB,
                                               float* __restrict__ Gcat) {
  __shared__ int Is[8][8]; __shared__ float Sg[8][8];
  build_oct_tables(threadIdx.x, Is, Sg);
  int g4 = blockIdx.x * 256 + threadIdx.x;
  int col = (g4 & 1023) * 4;
  int d = g4 >> 10;
  float4 v;
  if (col < 2048) {
    v.x = Wd[(size_t)(col + 0) * 1024 + d];
    v.y = Wd[(size_t)(col + 1) * 1024 + d];
    v.z = Wd[(size_t)(col + 2) * 1024 + d];
    v.w = Wd[(size_t)(col + 3) * 1024 + d];
  } else {
    int sp = col - 2048;
    int k = sp >> 8;
    int j = d >> 7, n = d & 127;
    int i = Is[j][k]; float sg = Sg[j][k];
    const float* wb = WB + (size_t)i * 32768 + n;
    v.x = sg * wb[(size_t)((sp + 0) & 255) * 128];
    v.y = sg * wb[(size_t)((sp + 1) & 255) * 128];
    v.z = sg * wb[(size_t)((sp + 2) & 255) * 128];
    v.w = sg * wb[(size_t)((sp + 3) & 255) * 128];
  }
  *(float4*)(Gcat + (size_t)g4 * 4) = v;
}

// CfT[s][d] = Cf[d][s]
__global__ __launch_bounds__(256) void fold_C(const float* __restrict__ WC, float* __restrict__ CfT) {
  __shared__ int Is[8][8]; __shared__ float Sg[8][8];
  build_oct_tables(threadIdx.x, Is, Sg);
  int g4 = blockIdx.x * 256 + threadIdx.x;
  int d0 = (g4 & 255) * 4;
  int s  = g4 >> 8;
  int j = s >> 8, n = s & 255;
  int k = d0 >> 7;
  int i = Is[j][k]; float sg = Sg[j][k];
  const float* wc = WC + (size_t)i * 32768 + n;
  float4 v;
  v.x = sg * wc[(size_t)((d0 + 0) & 127) * 256];
  v.y = sg * wc[(size_t)((d0 + 1) & 127) * 256];
  v.z = sg * wc[(size_t)((d0 + 2) & 127) * 256];
  v.w = sg * wc[(size_t)((d0 + 3) & 127) * 256];
  *(float4*)(CfT + (size_t)g4 * 4) = v;
}

// hx word layout: idx = chunk*64 + pair*8 + b ; word = {pk(hi32) | tag(lo32)}
// chunk c holds s = c*16 .. c*16+15; pair = (s&15)>>1; pk = bf16(h[s_even]) | bf16(h[s_even+1])<<16
__global__ __launch_bounds__(256) void init_h(const float* __restrict__ h_prev, unsigned long long* __restrict__ hx) {
  int gid = blockIdx.x * 256 + threadIdx.x;  // 0..16383
  if (gid < 8192) {
    int c = gid >> 6, within = gid & 63;
    int pr = within >> 3, b = within & 7;
    int s = c * 16 + pr * 2;
    unsigned pk = (unsigned)bf16r(h_prev[(size_t)b * 2048 + s])
                | ((unsigned)bf16r(h_prev[(size_t)b * 2048 + s + 1]) << 16);
    hx[gid] = ((unsigned long long)pk << 32) | 0ull;        // tag 0
  } else {
    hx[gid] = 0x00000000FFFFFFFFull;                        // buf1 sentinel tag
  }
}

// C = X[8192x1024] * Gcat[1024x4096]; cols<2048 -> sigmoid(+bias) -> delta[t][b][s]; else Bx[t][b][s]
__global__ __launch_bounds__(256) void gemm_dbx(const float* __restrict__ X, const float* __restrict__ G,
                                                const float* __restrict__ bias,
                                                float* __restrict__ dlt, float* __restrict__ Bx) {
  __shared__ float As[16][128];
  __shared__ float Bs[16][128];
  const int bn = blockIdx.x, bm = blockIdx.y;
  const int tid = threadIdx.x;
  const int tx = tid & 15, ty = tid >> 4;
  float acc[8][8] = {};
  for (int kt = 0; kt < 1024; kt += 16) {
    #pragma unroll
    for (int q = 0; q < 2; ++q) {
      int slot = tid * 2 + q;
      int r = slot >> 2, c4 = slot & 3;
      float4 v = *(const float4*)(X + (size_t)(bm * 128 + r) * 1024 + kt + c4 * 4);
      As[c4 * 4 + 0][r] = v.x; As[c4 * 4 + 1][r] = v.y;
      As[c4 * 4 + 2][r] = v.z; As[c4 * 4 + 3][r] = v.w;
    }
    #pragma unroll
    for (int q = 0; q < 2; ++q) {
      int slot = tid * 2 + q;
      int kr = slot >> 5, c4 = slot & 31;
      *(float4*)(&Bs[kr][c4 * 4]) = *(const float4*)(G + (size_t)(kt + kr) * 4096 + bn * 128 + c4 * 4);
    }
    __syncthreads();
    #pragma unroll
    for (int kk = 0; kk < 16; ++kk) {
      float a[8], b[8];
      #pragma unroll
      for (int i = 0; i < 8; ++i) a[i] = As[kk][ty + i * 16];
      #pragma unroll
      for (int j = 0; j < 8; ++j) b[j] = Bs[kk][tx + j * 16];
      #pragma unroll
      for (int i = 0; i < 8; ++i)
        #pragma unroll
        for (int j = 0; j < 8; ++j)
          acc[i][j] = fmaf(a[i], b[j], acc[i][j]);
    }
    __syncthreads();
  }
  const bool isDelta = (bn < 16);
  #pragma unroll
  for (int i = 0; i < 8; ++i) {
    int r = bm * 128 + ty + i * 16;
    int t = r & 1023, b = r >> 10;
    size_t base = ((size_t)t * 8 + b) * 2048;
    #pragma unroll
    for (int j = 0; j < 8; ++j) {
      int n = bn * 128 + tx + j * 16;
      float v = acc[i][j];
      if (isDelta) {
        v += bias[n];
        v = 1.0f / (1.0f + expf(-v));
        dlt[base + n] = v;
      } else {
        Bx[base + (n - 2048)] = v;
      }
    }
  }
}

// y[b][t][d] = sum_s hs[t*8+b][s] * CfT[s][d]
__global__ __launch_bounds__(256) void gemm_y(const float* __restrict__ HS, const float* __restrict__ CfT,
                                              float* __restrict__ out) {
  __shared__ float As[16][128];
  __shared__ float Bs[16][128];
  const int bn = blockIdx.x, bm = blockIdx.y;
  const int tid = threadIdx.x;
  const int tx = tid & 15, ty = tid >> 4;
  float acc[8][8] = {};
  for (int kt = 0; kt < 2048; kt += 16) {
    #pragma unroll
    for (int q = 0; q < 2; ++q) {
      int slot = tid * 2 + q;
      int r = slot >> 2, c4 = slot & 3;
      int rg = bm * 128 + r;
      const float* arow = HS + (size_t)((rg & 1023) * 8 + (rg >> 10)) * 2048;
      float4 v = *(const float4*)(arow + kt + c4 * 4);
      As[c4 * 4 + 0][r] = v.x; As[c4 * 4 + 1][r] = v.y;
      As[c4 * 4 + 2][r] = v.z; As[c4 * 4 + 3][r] = v.w;
    }
    #pragma unroll
    for (int q = 0; q < 2; ++q) {
      int slot = tid * 2 + q;
      int kr = slot >> 5, c4 = slot & 31;
      *(float4*)(&Bs[kr][c4 * 4]) = *(const float4*)(CfT + (size_t)(kt + kr) * 1024 + bn * 128 + c4 * 4);
    }
    __syncthreads();
    #pragma unroll
    for (int kk = 0; kk < 16; ++kk) {
      float a[8], b[8];
      #pragma unroll
      for (int i = 0; i < 8; ++i) a[i] = As[kk][ty + i * 16];
      #pragma unroll
      for (int j = 0; j < 8; ++j) b[j] = Bs[kk][tx + j * 16];
      #pragma unroll
      for (int i = 0; i < 8; ++i)
        #pragma unroll
        for (int j = 0; j < 8; ++j)
          acc[i][j] = fmaf(a[i], b[j], acc[i][j]);
    }
    __syncthreads();
  }
  #pragma unroll
  for (int i = 0; i < 8; ++i) {
    size_t rg = bm * 128 + ty + i * 16;
    #pragma unroll
    for (int j = 0; j < 8; ++j) {
      int n = bn * 128 + tx + j * 16;
      out[rg * 1024 + n] = acc[i][j];
    }
  }
}

// Persistent scan: 64 WGs x 512 threads, WG owns 32 sp rows (2 m-tiles). A-frags in registers (bf16).
// Exchange: self-tagged u64 words {bf16 pair | tag32}; fire-and-forget publish; stale-only re-load.
// Single barrier per step (red double-buffered); publish issued before history stores.
__global__ __launch_bounds__(512) void scan_kernel(const float* __restrict__ AfM, const float* __restrict__ dlt,
                                                   const float* __restrict__ Bx, float* __restrict__ hs,
                                                   unsigned long long* __restrict__ hx,
                                                   const float* __restrict__ h_prev, float* __restrict__ hlast) {
  __shared__ float red[2][16 * 144];       // [buf][(w*2+mt)][m(16) pitch 9]
  const int wg = blockIdx.x;               // 0..63
  const int tid = threadIdx.x;
  const int lane = tid & 63;
  const int w = tid >> 6;                  // wave 0..7 (K-slice of 256)
  const int row = lane & 15;               // A m-row (sp within tile) / D col n
  const int g4 = lane >> 4;                // k-group 0..3
  const int nb = lane & 7;                 // batch (cols 8..15 duplicate)

  // A-frags: afr[mt][q] = Af[wg*32+mt*16+row][w*256 + q*32 + g4*8 .. +7] in bf16
  short8 afr[2][8];
  #pragma unroll
  for (int mt = 0; mt < 2; ++mt) {
    const float* base = AfM + (size_t)(wg * 32 + mt * 16 + row) * 2048 + w * 256 + g4 * 8;
    #pragma unroll
    for (int q = 0; q < 8; ++q) {
      float4 f0 = *(const float4*)(base + q * 32);
      float4 f1 = *(const float4*)(base + q * 32 + 4);
      short8 v;
      v[0] = (short)bf16r(f0.x); v[1] = (short)bf16r(f0.y);
      v[2] = (short)bf16r(f0.z); v[3] = (short)bf16r(f0.w);
      v[4] = (short)bf16r(f1.x); v[5] = (short)bf16r(f1.y);
      v[6] = (short)bf16r(f1.z); v[7] = (short)bf16r(f1.w);
      afr[mt][q] = v;
    }
  }
  // consumer u64 base: word(q,p) = ubase + q*128 + p*8
  const int ubase = w * 1024 + (g4 >> 1) * 64 + (g4 & 1) * 32 + nb;

  // producer lanes (tid < 128, waves 0-1): ub = batch, pairIdx = sp-pair 0..15
  const int ub = tid >> 4, pairIdx = tid & 15;
  const int psl = pairIdx * 2;                       // sp_local 0..30
  const int pmt = pairIdx >> 3, pm = (pairIdx & 7) * 2;
  const int pword = wg * 128 + (pairIdx >> 3) * 64 + (pairIdx & 7) * 8 + ub;
  float hr0 = 0.f, hr1 = 0.f;
  if (tid < 128) {
    hr0 = h_prev[(size_t)ub * 2048 + wg * 32 + psl];
    hr1 = h_prev[(size_t)ub * 2048 + wg * 32 + psl + 1];
  }

  #pragma unroll 1
  for (int t = 0; t < T_STEPS; ++t) {
    float2 dv = make_float2(0.f, 0.f), bxv = make_float2(0.f, 0.f);
    if (tid < 128) {
      size_t off = ((size_t)t * 8 + ub) * 2048 + wg * 32 + psl;
      dv  = *(const float2*)(dlt + off);
      bxv = *(const float2*)(Bx + off);
    }
    const unsigned want = (unsigned)t;
    const unsigned long long* bq = hx + (size_t)(t & 1) * 8192;
    unsigned long long wv[32];
    #pragma unroll
    for (int j = 0; j < 32; ++j)
      wv[j] = __hip_atomic_load(bq + ubase + (j >> 2) * 128 + (j & 3) * 8,
                                __ATOMIC_RELAXED, __HIP_MEMORY_SCOPE_SYSTEM);
    for (;;) {
      bool stale = false;
      #pragma unroll
      for (int j = 0; j < 32; ++j) stale |= ((unsigned)wv[j] != want);
      if (!__any(stale)) break;
      #pragma unroll
      for (int j = 0; j < 32; ++j)
        if ((unsigned)wv[j] != want)
          wv[j] = __hip_atomic_load(bq + ubase + (j >> 2) * 128 + (j & 3) * 8,
                                    __ATOMIC_RELAXED, __HIP_MEMORY_SCOPE_SYSTEM);
    }
    f32x4 acc0 = {0.f, 0.f, 0.f, 0.f}, acc1 = {0.f, 0.f, 0.f, 0.f};
    #pragma unroll
    for (int q = 0; q < 8; ++q) {
      union { unsigned d[4]; short8 v; } bb;
      bb.d[0] = (unsigned)(wv[q * 4 + 0] >> 32);
      bb.d[1] = (unsigned)(wv[q * 4 + 1] >> 32);
      bb.d[2] = (unsigned)(wv[q * 4 + 2] >> 32);
      bb.d[3] = (unsigned)(wv[q * 4 + 3] >> 32);
      acc0 = __builtin_amdgcn_mfma_f32_16x16x32_bf16(afr[0][q], bb.v, acc0, 0, 0, 0);
      acc1 = __builtin_amdgcn_mfma_f32_16x16x32_bf16(afr[1][q], bb.v, acc1, 0, 0, 0);
    }
    // partial D -> LDS; element (m = g4*4+r, n = row), valid n<8
    float* rb = &red[t & 1][0];
    if (row < 8) {
      #pragma unroll
      for (int r = 0; r < 4; ++r) {
        rb[(w * 2 + 0) * 144 + (g4 * 4 + r) * 9 + row] = acc0[r];
        rb[(w * 2 + 1) * 144 + (g4 * 4 + r) * 9 + row] = acc1[r];
      }
    }
    __syncthreads();
    if (tid < 128) {
      float o0 = 0.f, o1 = 0.f;
      #pragma unroll
      for (int ww = 0; ww < 8; ++ww) {
        o0 += rb[(ww * 2 + pmt) * 144 + pm * 9 + ub];
        o1 += rb[(ww * 2 + pmt) * 144 + (pm + 1) * 9 + ub];
      }
      float h0 = fmaf(dv.x, o0 + bxv.x - hr0, hr0);
      float h1 = fmaf(dv.y, o1 + bxv.y - hr1, hr1);
      hr0 = h0; hr1 = h1;
      unsigned pk = (unsigned)bf16r(h0) | ((unsigned)bf16r(h1) << 16);
      unsigned long long wval = ((unsigned long long)pk << 32) | (unsigned long long)(unsigned)(t + 1);
      __hip_atomic_store(hx + (size_t)((t + 1) & 1) * 8192 + pword, wval,
                         __ATOMIC_RELAXED, __HIP_MEMORY_SCOPE_SYSTEM);   // publish first
      size_t off = ((size_t)t * 8 + ub) * 2048 + wg * 32 + psl;
      *(float2*)(hs + off) = make_float2(h0, h1);
      if (t == T_STEPS - 1)
        *(float2*)(hlast + (size_t)ub * 2048 + wg * 32 + psl) = make_float2(h0, h1);
    }
    // no second barrier: red is double-buffered; next-step writes target red[(t+1)&1]
  }
}

extern "C" void kernel_launch(void* const* d_in, const int* in_sizes, int n_in,
                              void* d_out, int out_size, void* d_ws, size_t ws_size,
                              hipStream_t stream) {
  const float* x      = (const float*)d_in[0];
  const float* h_prev = (const float*)d_in[1];
  const float* WA     = (const float*)d_in[2];
  const float* WB     = (const float*)d_in[3];
  const float* WC     = (const float*)d_in[4];
  const float* Wd     = (const float*)d_in[5];
  const float* bias   = (const float*)d_in[6];
  float* out = (float*)d_out;
  float* w = (float*)d_ws;
  float* AfM  = w + OFF_AFT;
  float* Gcat = w + OFF_GCAT;
  float* CfT  = w + OFF_CFT;
  float* dlt  = w + OFF_DELTA;
  float* Bx   = w + OFF_BX;
  float* hs   = w + OFF_HS;
  unsigned long long* hx = (unsigned long long*)(w + OFF_HBUF);

  fold_A <<<4096, 256, 0, stream>>>(WA, AfM);
  fold_GC<<<4096, 256, 0, stream>>>(Wd, WB, Gcat);
  fold_C <<<2048, 256, 0, stream>>>(WC, CfT);
  init_h <<<64,   256, 0, stream>>>(h_prev, hx);
  gemm_dbx<<<dim3(32, 64), 256, 0, stream>>>(x, Gcat, bias, dlt, Bx);
  scan_kernel<<<64, 512, 0, stream>>>(AfM, dlt, Bx, hs, hx, h_prev, out + 8388608);
  gemm_y<<<dim3(8, 64), 256, 0, stream>>>(hs, CfT, out);
}